// Round 3
// baseline (100.788 us; speedup 1.0000x reference)
//
#include <hip/hip_runtime.h>

#define BATCH 16
#define TOK   4096
#define DIM   768
#define SMAX  128
#define BM    8     // rows per MLP block

__device__ __forceinline__ int lower_bound_i(const int* __restrict__ a, int n, int v) {
    int lo = 0, hi = n;
    while (lo < hi) {
        int m = (lo + hi) >> 1;
        if (a[m] < v) lo = m + 1; else hi = m;
    }
    return lo;
}

__device__ __forceinline__ float f4get(const float4& v, int k) {
    switch (k) {
        case 0: return v.x;
        case 1: return v.y;
        case 2: return v.z;
        default: return v.w;
    }
}

// Kernel A: per-(b,s) segment sum over contiguous sorted token span.
// grid (SMAX, BATCH), 192 threads; each thread owns one float4 column of D=768.
__global__ __launch_bounds__(192)
void segsum_kernel(const float* __restrict__ hidden,
                   const int* __restrict__ seg,
                   float* __restrict__ sent) {
    const int s = blockIdx.x;
    const int b = blockIdx.y;
    const int tid = threadIdx.x;

    const int* srow = seg + b * TOK;
    const int lo = lower_bound_i(srow, TOK, s);
    const int hi = lower_bound_i(srow, TOK, s + 1);

    float4 acc = make_float4(0.f, 0.f, 0.f, 0.f);
    const float4* hrow = reinterpret_cast<const float4*>(hidden + (size_t)b * TOK * DIM);
    for (int t = lo; t < hi; ++t) {
        float4 v = hrow[(size_t)t * (DIM / 4) + tid];
        acc.x += v.x; acc.y += v.y; acc.z += v.z; acc.w += v.w;
    }
    float4* outp = reinterpret_cast<float4*>(sent + (size_t)(b * SMAX + s) * DIM);
    outp[tid] = acc;
}

// Kernel B: fused MLP head over BM rows per block.
// layer1: 768->384 relu; layer2: 384->128 relu; layer3: 128->2.
__global__ __launch_bounds__(256)
void mlp_kernel(const float* __restrict__ sent,
                const float* __restrict__ W1, const float* __restrict__ b1,
                const float* __restrict__ W2, const float* __restrict__ b2,
                const float* __restrict__ W3, const float* __restrict__ b3,
                float* __restrict__ out) {
    __shared__ float A[BM][DIM];     // 24 KB
    __shared__ float X1[BM][384];    // 12 KB
    __shared__ float X2[BM][128];    // 4 KB

    const int tid = threadIdx.x;
    const int row0 = blockIdx.x * BM;

    // Stage A tile: BM*DIM = 6144 floats = 1536 float4, 256 threads -> 6 each
    {
        const float4* src = reinterpret_cast<const float4*>(sent + (size_t)row0 * DIM);
        float4* dst = reinterpret_cast<float4*>(&A[0][0]);
        #pragma unroll
        for (int i = 0; i < (BM * DIM / 4) / 256; ++i)
            dst[tid + i * 256] = src[tid + i * 256];
    }
    __syncthreads();

    const int c1 = tid & 127;   // column within 128-group
    const int g  = tid >> 7;    // row group 0/1 (rows 4g..4g+3)

    // ---- layer 1: acc[4 rows][3 cols] over k=0..767 ----
    float acc[4][3];
    #pragma unroll
    for (int i = 0; i < 4; ++i)
        #pragma unroll
        for (int j = 0; j < 3; ++j) acc[i][j] = 0.f;

    for (int k = 0; k < DIM; k += 4) {
        float4 a[4];
        #pragma unroll
        for (int i = 0; i < 4; ++i)
            a[i] = *reinterpret_cast<const float4*>(&A[g * 4 + i][k]);
        #pragma unroll
        for (int kk = 0; kk < 4; ++kk) {
            const float w0 = W1[(k + kk) * 384 + c1];
            const float w1 = W1[(k + kk) * 384 + c1 + 128];
            const float w2 = W1[(k + kk) * 384 + c1 + 256];
            #pragma unroll
            for (int i = 0; i < 4; ++i) {
                const float av = f4get(a[i], kk);
                acc[i][0] = fmaf(av, w0, acc[i][0]);
                acc[i][1] = fmaf(av, w1, acc[i][1]);
                acc[i][2] = fmaf(av, w2, acc[i][2]);
            }
        }
    }
    #pragma unroll
    for (int j = 0; j < 3; ++j) {
        const float bb = b1[c1 + j * 128];
        #pragma unroll
        for (int i = 0; i < 4; ++i) {
            const float v = acc[i][j] + bb;
            X1[g * 4 + i][c1 + j * 128] = v > 0.f ? v : 0.f;
        }
    }
    __syncthreads();

    // ---- layer 2: acc2[4 rows] for column c1 over k=0..383 ----
    float acc2[4] = {0.f, 0.f, 0.f, 0.f};
    for (int k = 0; k < 384; k += 4) {
        float4 a[4];
        #pragma unroll
        for (int i = 0; i < 4; ++i)
            a[i] = *reinterpret_cast<const float4*>(&X1[g * 4 + i][k]);
        #pragma unroll
        for (int kk = 0; kk < 4; ++kk) {
            const float w = W2[(k + kk) * 128 + c1];
            #pragma unroll
            for (int i = 0; i < 4; ++i)
                acc2[i] = fmaf(f4get(a[i], kk), w, acc2[i]);
        }
    }
    {
        const float bb = b2[c1];
        #pragma unroll
        for (int i = 0; i < 4; ++i) {
            const float v = acc2[i] + bb;
            X2[g * 4 + i][c1] = v > 0.f ? v : 0.f;
        }
    }
    __syncthreads();

    // ---- layer 3: BM*2 = 16 outputs ----
    if (tid < BM * 2) {
        const int r = tid >> 1;
        const int c = tid & 1;
        float sacc = 0.f;
        #pragma unroll 8
        for (int k = 0; k < 128; ++k)
            sacc = fmaf(X2[r][k], W3[k * 2 + c], sacc);
        out[(row0 + r) * 2 + c] = sacc + b3[c];
    }
}

extern "C" void kernel_launch(void* const* d_in, const int* in_sizes, int n_in,
                              void* d_out, int out_size, void* d_ws, size_t ws_size,
                              hipStream_t stream) {
    const float* hidden = (const float*)d_in[0];
    const int*   seg    = (const int*)d_in[1];
    const float* W1     = (const float*)d_in[2];
    const float* b1     = (const float*)d_in[3];
    const float* W2     = (const float*)d_in[4];
    const float* b2     = (const float*)d_in[5];
    const float* W3     = (const float*)d_in[6];
    const float* b3     = (const float*)d_in[7];
    float* out  = (float*)d_out;
    float* sent = (float*)d_ws;  // BATCH*SMAX*DIM floats = 6 MB

    segsum_kernel<<<dim3(SMAX, BATCH), 192, 0, stream>>>(hidden, seg, sent);
    mlp_kernel<<<(BATCH * SMAX) / BM, 256, 0, stream>>>(sent, W1, b1, W2, b2, W3, b3, out);
}

// Round 4
// 99.729 us; speedup vs baseline: 1.0106x; 1.0106x over previous
//
#include <hip/hip_runtime.h>

#define BATCH 16
#define TOK   4096
#define DIM   768
#define SMAX  128
#define BM    8     // rows per MLP block

__device__ __forceinline__ int lower_bound_i(const int* __restrict__ a, int n, int v) {
    int lo = 0, hi = n;
    while (lo < hi) {
        int m = (lo + hi) >> 1;
        if (a[m] < v) lo = m + 1; else hi = m;
    }
    return lo;
}

__device__ __forceinline__ float f4get(const float4& v, int k) {
    switch (k) {
        case 0: return v.x;
        case 1: return v.y;
        case 2: return v.z;
        default: return v.w;
    }
}

__device__ __forceinline__ void f4acc(float4& a, const float4& v) {
    a.x += v.x; a.y += v.y; a.z += v.z; a.w += v.w;
}

// Kernel A: per-(b,s) segment sum over contiguous sorted token span.
// grid (SMAX, BATCH), 192 threads; each thread owns one float4 column of D=768.
// 16-deep manual load pipeline: ~16 KB in flight per wave so ~20 waves/CU
// reach the ~294 KB/CU latency-BW product HBM needs.
__global__ __launch_bounds__(192)
void segsum_kernel(const float* __restrict__ hidden,
                   const int* __restrict__ seg,
                   float* __restrict__ sent) {
    const int s = blockIdx.x;
    const int b = blockIdx.y;
    const int tid = threadIdx.x;

    const int* srow = seg + b * TOK;
    const int lo = lower_bound_i(srow, TOK, s);
    const int hi = lower_bound_i(srow, TOK, s + 1);

    const float4* __restrict__ hp =
        reinterpret_cast<const float4*>(hidden + (size_t)b * TOK * DIM) + tid;

    float4 acc = make_float4(0.f, 0.f, 0.f, 0.f);
    int t = lo;

    // 16-deep main loop: issue all 16 loads (independent), then reduce.
    for (; t + 16 <= hi; t += 16) {
        float4 v[16];
        #pragma unroll
        for (int u = 0; u < 16; ++u)
            v[u] = hp[(size_t)(t + u) * (DIM / 4)];
        #pragma unroll
        for (int u = 0; u < 16; ++u)
            f4acc(acc, v[u]);
    }
    // 4-deep tail
    for (; t + 4 <= hi; t += 4) {
        float4 v[4];
        #pragma unroll
        for (int u = 0; u < 4; ++u)
            v[u] = hp[(size_t)(t + u) * (DIM / 4)];
        #pragma unroll
        for (int u = 0; u < 4; ++u)
            f4acc(acc, v[u]);
    }
    for (; t < hi; ++t)
        f4acc(acc, hp[(size_t)t * (DIM / 4)]);

    float4* outp = reinterpret_cast<float4*>(sent + (size_t)(b * SMAX + s) * DIM);
    outp[tid] = acc;
}

// Kernel B: fused MLP head over BM rows per block. (unchanged this round)
// layer1: 768->384 relu; layer2: 384->128 relu; layer3: 128->2.
__global__ __launch_bounds__(256)
void mlp_kernel(const float* __restrict__ sent,
                const float* __restrict__ W1, const float* __restrict__ b1,
                const float* __restrict__ W2, const float* __restrict__ b2,
                const float* __restrict__ W3, const float* __restrict__ b3,
                float* __restrict__ out) {
    __shared__ float A[BM][DIM];     // 24 KB
    __shared__ float X1[BM][384];    // 12 KB
    __shared__ float X2[BM][128];    // 4 KB

    const int tid = threadIdx.x;
    const int row0 = blockIdx.x * BM;

    // Stage A tile: BM*DIM = 6144 floats = 1536 float4, 256 threads -> 6 each
    {
        const float4* src = reinterpret_cast<const float4*>(sent + (size_t)row0 * DIM);
        float4* dst = reinterpret_cast<float4*>(&A[0][0]);
        #pragma unroll
        for (int i = 0; i < (BM * DIM / 4) / 256; ++i)
            dst[tid + i * 256] = src[tid + i * 256];
    }
    __syncthreads();

    const int c1 = tid & 127;   // column within 128-group
    const int g  = tid >> 7;    // row group 0/1 (rows 4g..4g+3)

    // ---- layer 1: acc[4 rows][3 cols] over k=0..767 ----
    float acc[4][3];
    #pragma unroll
    for (int i = 0; i < 4; ++i)
        #pragma unroll
        for (int j = 0; j < 3; ++j) acc[i][j] = 0.f;

    for (int k = 0; k < DIM; k += 4) {
        float4 a[4];
        #pragma unroll
        for (int i = 0; i < 4; ++i)
            a[i] = *reinterpret_cast<const float4*>(&A[g * 4 + i][k]);
        #pragma unroll
        for (int kk = 0; kk < 4; ++kk) {
            const float w0 = W1[(k + kk) * 384 + c1];
            const float w1 = W1[(k + kk) * 384 + c1 + 128];
            const float w2 = W1[(k + kk) * 384 + c1 + 256];
            #pragma unroll
            for (int i = 0; i < 4; ++i) {
                const float av = f4get(a[i], kk);
                acc[i][0] = fmaf(av, w0, acc[i][0]);
                acc[i][1] = fmaf(av, w1, acc[i][1]);
                acc[i][2] = fmaf(av, w2, acc[i][2]);
            }
        }
    }
    #pragma unroll
    for (int j = 0; j < 3; ++j) {
        const float bb = b1[c1 + j * 128];
        #pragma unroll
        for (int i = 0; i < 4; ++i) {
            const float v = acc[i][j] + bb;
            X1[g * 4 + i][c1 + j * 128] = v > 0.f ? v : 0.f;
        }
    }
    __syncthreads();

    // ---- layer 2: acc2[4 rows] for column c1 over k=0..383 ----
    float acc2[4] = {0.f, 0.f, 0.f, 0.f};
    for (int k = 0; k < 384; k += 4) {
        float4 a[4];
        #pragma unroll
        for (int i = 0; i < 4; ++i)
            a[i] = *reinterpret_cast<const float4*>(&X1[g * 4 + i][k]);
        #pragma unroll
        for (int kk = 0; kk < 4; ++kk) {
            const float w = W2[(k + kk) * 128 + c1];
            #pragma unroll
            for (int i = 0; i < 4; ++i)
                acc2[i] = fmaf(f4get(a[i], kk), w, acc2[i]);
        }
    }
    {
        const float bb = b2[c1];
        #pragma unroll
        for (int i = 0; i < 4; ++i) {
            const float v = acc2[i] + bb;
            X2[g * 4 + i][c1] = v > 0.f ? v : 0.f;
        }
    }
    __syncthreads();

    // ---- layer 3: BM*2 = 16 outputs ----
    if (tid < BM * 2) {
        const int r = tid >> 1;
        const int c = tid & 1;
        float sacc = 0.f;
        #pragma unroll 8
        for (int k = 0; k < 128; ++k)
            sacc = fmaf(X2[r][k], W3[k * 2 + c], sacc);
        out[(row0 + r) * 2 + c] = sacc + b3[c];
    }
}

extern "C" void kernel_launch(void* const* d_in, const int* in_sizes, int n_in,
                              void* d_out, int out_size, void* d_ws, size_t ws_size,
                              hipStream_t stream) {
    const float* hidden = (const float*)d_in[0];
    const int*   seg    = (const int*)d_in[1];
    const float* W1     = (const float*)d_in[2];
    const float* b1     = (const float*)d_in[3];
    const float* W2     = (const float*)d_in[4];
    const float* b2     = (const float*)d_in[5];
    const float* W3     = (const float*)d_in[6];
    const float* b3     = (const float*)d_in[7];
    float* out  = (float*)d_out;
    float* sent = (float*)d_ws;  // BATCH*SMAX*DIM floats = 6 MB

    segsum_kernel<<<dim3(SMAX, BATCH), 192, 0, stream>>>(hidden, seg, sent);
    mlp_kernel<<<(BATCH * SMAX) / BM, 256, 0, stream>>>(sent, W1, b1, W2, b2, W3, b3, out);
}